// Round 2
// baseline (591.449 us; speedup 1.0000x reference)
//
#include <hip/hip_runtime.h>
#include <stdint.h>

#define N_NODES 50000
#define N_EDGES 800000
#define BB 2
#define F0 216
#define ROWS (BB*N_NODES)   // 100000
#define BN_EPS 1e-5f
#define NSB 49              // ceil(N_NODES/1024)

// ---------------- CSR build ----------------
// edge_index arrives as int32 [2, E]  (harness stages integer inputs as int32)

__global__ void k_count(const int* __restrict__ ei, int* __restrict__ cnt) {
    int e = blockIdx.x*blockDim.x + threadIdx.x;
    if (e < N_EDGES) {
        int c = ei[N_EDGES + e];     // col (destination)
        atomicAdd(&cnt[c], 1);
    }
}

__global__ void k_dinv(const int* __restrict__ cnt, float* __restrict__ dinv) {
    int i = blockIdx.x*blockDim.x + threadIdx.x;
    if (i < N_NODES) dinv[i] = rsqrtf((float)(cnt[i] + 1));  // +1 self loop
}

__global__ void k_scanA(const int* __restrict__ cnt, int* __restrict__ incl, int* __restrict__ part) {
    __shared__ int s[1024];
    int t = threadIdx.x;
    int i = blockIdx.x*1024 + t;
    s[t] = (i < N_NODES) ? cnt[i] : 0;
    __syncthreads();
    for (int off=1; off<1024; off<<=1) {
        int a = (t >= off) ? s[t-off] : 0;
        __syncthreads();
        s[t] += a;
        __syncthreads();
    }
    if (i < N_NODES) incl[i] = s[t];
    if (t == 1023) part[blockIdx.x] = s[t];
}

__global__ void k_scanB(int* part) {
    if (threadIdx.x == 0 && blockIdx.x == 0) {
        int run = 0;
        for (int b=0; b<NSB; b++) { int v = part[b]; part[b] = run; run += v; }
    }
}

__global__ void k_scanC(const int* __restrict__ cnt, const int* __restrict__ incl, const int* __restrict__ part,
                        int* __restrict__ offs, int* __restrict__ cursor) {
    int i = blockIdx.x*1024 + threadIdx.x;
    if (i < N_NODES) {
        int inc = part[blockIdx.x] + incl[i];
        int ex = inc - cnt[i];
        offs[i] = ex; cursor[i] = ex;
        if (i == N_NODES-1) offs[N_NODES] = inc;
    }
}

__global__ void k_fill(const int* __restrict__ ei, const float* __restrict__ dinv,
                       int* __restrict__ cursor, int* __restrict__ csr_src, float* __restrict__ csr_w) {
    int e = blockIdx.x*blockDim.x + threadIdx.x;
    if (e < N_EDGES) {
        int r = ei[e];
        int c = ei[N_EDGES + e];
        int slot = atomicAdd(&cursor[c], 1);
        csr_src[slot] = r;
        csr_w[slot]  = dinv[r];
    }
}

// ---------------- Layer 1 GEMM: xw[100k,64] = x[100k,216] @ W1 ----------------
__global__ __launch_bounds__(256) void k_gemm1(const float* __restrict__ x, const float* __restrict__ W1,
                                               float* __restrict__ xw) {
    __shared__ float xs[64*F0];     // 55296 B
    int t = threadIdx.x;
    int row0 = blockIdx.x * 64;
    int validFloats = (ROWS - row0) * F0;
    const float4* xg = reinterpret_cast<const float4*>(x + (size_t)row0 * F0);
    float4* xs4 = reinterpret_cast<float4*>(xs);
    float4 z; z.x=z.y=z.z=z.w=0.f;
    for (int idx = t; idx < (64*F0)/4; idx += 256)
        xs4[idx] = (idx*4 < validFloats) ? xg[idx] : z;
    __syncthreads();

    int o2 = t & 31;          // output col, also +32
    int rg = t >> 5;          // 0..7 row groups of 8
    float accA[8], accB[8];
    #pragma unroll
    for (int j=0;j<8;j++){ accA[j]=0.f; accB[j]=0.f; }
    const float4* xv = reinterpret_cast<const float4*>(xs + rg*8*F0);
    for (int k4=0; k4<F0/4; k4++) {
        float wA[4], wB[4];
        #pragma unroll
        for (int i=0;i<4;i++){
            wA[i] = W1[(4*k4+i)*64 + o2];
            wB[i] = W1[(4*k4+i)*64 + o2 + 32];
        }
        #pragma unroll
        for (int j=0;j<8;j++) {
            float4 xj = xv[j*(F0/4) + k4];
            accA[j] += xj.x*wA[0] + xj.y*wA[1] + xj.z*wA[2] + xj.w*wA[3];
            accB[j] += xj.x*wB[0] + xj.y*wB[1] + xj.z*wB[2] + xj.w*wB[3];
        }
    }
    #pragma unroll
    for (int j=0;j<8;j++) {
        int grow = row0 + rg*8 + j;
        if (grow < ROWS) {
            xw[(size_t)grow*64 + o2]      = accA[j];
            xw[(size_t)grow*64 + o2 + 32] = accB[j];
        }
    }
}

// ---------------- Propagate 1 (64 feat) + bias + relu + BN1 stats ----------------
__global__ __launch_bounds__(256) void k_prop1(const float* __restrict__ xw, const int* __restrict__ offs,
                       const int* __restrict__ csr_src, const float* __restrict__ csr_w,
                       const float* __restrict__ dinv, const float* __restrict__ b1,
                       float* __restrict__ h, float* __restrict__ stat) {
    __shared__ float lsum[64], lsq[64];
    int t = threadIdx.x;
    if (t < 64) { lsum[t]=0.f; lsq[t]=0.f; }
    __syncthreads();
    int f = t & 63;
    int wid = blockIdx.x*4 + (t>>6);
    int nwaves = gridDim.x*4;
    float bias = b1[f];
    float ls=0.f, lq=0.f;
    for (int d = wid; d < N_NODES; d += nwaves) {
        int s0 = offs[d], s1 = offs[d+1];
        float a0=0.f, a1=0.f;
        for (int e=s0; e<s1; e++) {
            int src = csr_src[e];
            float w = csr_w[e];
            a0 += w * xw[(size_t)src*64 + f];
            a1 += w * xw[(size_t)(N_NODES+src)*64 + f];
        }
        float sd = dinv[d];
        a0 += sd * xw[(size_t)d*64 + f];
        a1 += sd * xw[(size_t)(N_NODES+d)*64 + f];
        float h0 = fmaxf(sd*a0 + bias, 0.f);
        float h1 = fmaxf(sd*a1 + bias, 0.f);
        h[(size_t)d*64 + f] = h0;
        h[(size_t)(N_NODES+d)*64 + f] = h1;
        ls += h0 + h1;
        lq += h0*h0 + h1*h1;
    }
    atomicAdd(&lsum[f], ls);
    atomicAdd(&lsq[f], lq);
    __syncthreads();
    if (t < 64) {
        atomicAdd(&stat[t],     lsum[t]);
        atomicAdd(&stat[64+t],  lsq[t]);
    }
}

// ---------------- BN finalize -> scale/shift ----------------
__global__ void k_bnfin(const float* __restrict__ stat, const float* __restrict__ g,
                        const float* __restrict__ be, float* __restrict__ sc, int C) {
    int f = threadIdx.x;
    if (f < C) {
        float inv_n = 1.0f / (float)(BB*N_NODES);
        float mean = stat[f]*inv_n;
        float var  = stat[C+f]*inv_n - mean*mean;
        float is   = rsqrtf(var + BN_EPS);
        float scale = g[f]*is;
        sc[f]   = scale;
        sc[C+f] = be[f] - mean*scale;
    }
}

// ---------------- BN1 apply + GEMM2 (64->8) ----------------
__global__ __launch_bounds__(256) void k_bn1_gemm2(const float* __restrict__ h, const float* __restrict__ sc1,
                        const float* __restrict__ W2, float* __restrict__ t2) {
    __shared__ float hs[32][68];
    __shared__ float w2s[64*8];
    int t = threadIdx.x;
    for (int i=t; i<512; i+=256) w2s[i] = W2[i];
    int row0 = blockIdx.x*32;
    for (int idx=t; idx<2048; idx+=256) {
        int r = idx>>6, f = idx&63;
        int grow = row0 + r;
        hs[r][f] = (grow < ROWS) ? h[(size_t)grow*64+f]*sc1[f] + sc1[64+f] : 0.f;
    }
    __syncthreads();
    int r = t >> 3, o = t & 7;
    float acc = 0.f;
    #pragma unroll
    for (int f=0; f<64; f++) acc += hs[r][f] * w2s[f*8+o];
    int grow = row0 + r;
    if (grow < ROWS) t2[(size_t)grow*8 + o] = acc;
}

// ---------------- Propagate 2 (8 feat) -> x1 out; relu + BN2 stats ----------------
__global__ __launch_bounds__(256) void k_prop2(const float* __restrict__ t2, const int* __restrict__ offs,
                       const int* __restrict__ csr_src, const float* __restrict__ csr_w,
                       const float* __restrict__ dinv, const float* __restrict__ b2,
                       float* __restrict__ x1_out, float* __restrict__ stat) {
    __shared__ float lsum[8], lsq[8];
    int t = threadIdx.x;
    if (t < 8) { lsum[t]=0.f; lsq[t]=0.f; }
    __syncthreads();
    int lane = t & 63;
    int o = lane & 7, b = (lane>>3)&1, es = lane>>4;   // 4 edge-lanes
    int wid = blockIdx.x*4 + (t>>6);
    int nwaves = gridDim.x*4;
    float bias = b2[o];
    float ls=0.f, lq=0.f;
    for (int d=wid; d<N_NODES; d+=nwaves) {
        int s0=offs[d], s1=offs[d+1];
        float acc=0.f;
        for (int e=s0+es; e<s1; e+=4) {
            acc += csr_w[e] * t2[(size_t)(b*N_NODES+csr_src[e])*8 + o];
        }
        acc += __shfl_xor(acc, 16, 64);
        acc += __shfl_xor(acc, 32, 64);
        float sd = dinv[d];
        float val = sd*(acc + sd*t2[(size_t)(b*N_NODES+d)*8 + o]) + bias;
        if (es == 0) {
            x1_out[(size_t)(b*N_NODES+d)*8 + o] = val;
            float rv = fmaxf(val, 0.f);
            ls += rv; lq += rv*rv;
        }
    }
    if (es == 0) { atomicAdd(&lsum[o], ls); atomicAdd(&lsq[o], lq); }
    __syncthreads();
    if (t < 8) { atomicAdd(&stat[t], lsum[t]); atomicAdd(&stat[8+t], lsq[t]); }
}

// ---------------- BN2 apply + GEMM3 (8->3), padded to 4 ----------------
__global__ void k_bn2_gemm3(const float* __restrict__ x1, const float* __restrict__ sc2,
                            const float* __restrict__ W3, float* __restrict__ t3) {
    int rowi = blockIdx.x*blockDim.x + threadIdx.x;
    if (rowi < ROWS) {
        float v[8];
        #pragma unroll
        for (int o=0;o<8;o++) {
            float r = fmaxf(x1[(size_t)rowi*8+o], 0.f);
            v[o] = r*sc2[o] + sc2[8+o];
        }
        #pragma unroll
        for (int c=0;c<3;c++) {
            float acc=0.f;
            #pragma unroll
            for (int o=0;o<8;o++) acc += v[o]*W3[o*3+c];
            t3[(size_t)rowi*4+c] = acc;
        }
        t3[(size_t)rowi*4+3] = 0.f;
    }
}

// ---------------- Propagate 3 (3 feat) + b3 -> final out ----------------
__global__ __launch_bounds__(256) void k_prop3(const float* __restrict__ t3, const int* __restrict__ offs,
                       const int* __restrict__ csr_src, const float* __restrict__ csr_w,
                       const float* __restrict__ dinv, const float* __restrict__ b3,
                       float* __restrict__ outp) {
    int t = threadIdx.x;
    int lane = t & 63;
    int c = lane & 3, b = (lane>>2)&1, es = lane>>3;   // 8 edge-lanes
    int wid = blockIdx.x*4 + (t>>6);
    int nwaves = gridDim.x*4;
    float bias = (c<3) ? b3[c] : 0.f;
    for (int d=wid; d<N_NODES; d+=nwaves) {
        int s0=offs[d], s1=offs[d+1];
        float acc=0.f;
        for (int e=s0+es; e<s1; e+=8) {
            acc += csr_w[e] * t3[(size_t)(b*N_NODES+csr_src[e])*4 + c];
        }
        acc += __shfl_xor(acc, 8, 64);
        acc += __shfl_xor(acc, 16, 64);
        acc += __shfl_xor(acc, 32, 64);
        float sd = dinv[d];
        float val = sd*(acc + sd*t3[(size_t)(b*N_NODES+d)*4 + c]) + bias;
        if (es == 0 && c < 3) outp[(size_t)(b*N_NODES+d)*3 + c] = val;
    }
}

// ---------------- launch ----------------
static inline size_t align256(size_t x){ return (x + 255) & ~(size_t)255; }

extern "C" void kernel_launch(void* const* d_in, const int* in_sizes, int n_in,
                              void* d_out, int out_size, void* d_ws, size_t ws_size,
                              hipStream_t stream) {
    const float* x   = (const float*)d_in[0];
    const float* W1  = (const float*)d_in[1];
    const float* b1  = (const float*)d_in[2];
    const float* g1  = (const float*)d_in[3];
    const float* be1 = (const float*)d_in[4];
    const float* W2  = (const float*)d_in[5];
    const float* b2  = (const float*)d_in[6];
    const float* g2  = (const float*)d_in[7];
    const float* be2 = (const float*)d_in[8];
    const float* W3  = (const float*)d_in[9];
    const float* b3  = (const float*)d_in[10];
    const int*   ei  = (const int*)d_in[11];     // int32 [2, E] per harness contract

    float* outp   = (float*)d_out;                 // [B,N,3] = 300000
    float* x1_out = (float*)d_out + BB*N_NODES*3;  // [B,N,8] = 800000

    // workspace bump allocator (zeroed region first)
    char* w = (char*)d_ws;
    size_t off = 0;
    auto alloc = [&](size_t bytes) { void* p = w + off; off = align256(off + bytes); return p; };
    int*   cnt    = (int*)  alloc(N_NODES*4);
    float* stat1  = (float*)alloc(128*4);
    float* stat2  = (float*)alloc(16*4);
    size_t zero_bytes = off;
    float* dinv   = (float*)alloc(N_NODES*4);
    int*   incl   = (int*)  alloc(N_NODES*4);
    int*   part   = (int*)  alloc(64*4);
    int*   offs   = (int*)  alloc((N_NODES+1)*4);
    int*   cursor = (int*)  alloc(N_NODES*4);
    int*   csr_src= (int*)  alloc((size_t)N_EDGES*4);
    float* csr_w  = (float*)alloc((size_t)N_EDGES*4);
    float* xw     = (float*)alloc((size_t)ROWS*64*4);
    float* h      = (float*)alloc((size_t)ROWS*64*4);
    float* sc1    = (float*)alloc(128*4);
    float* sc2    = (float*)alloc(16*4);
    // aliases onto dead buffers (reduce footprint): t2 over xw, t3 over h
    float* t2     = xw;      // xw dead after k_prop1; t2 written by k_bn1_gemm2
    float* t3     = h;       // h dead after k_bn1_gemm2; t3 written by k_bn2_gemm3
    (void)ws_size; (void)in_sizes; (void)n_in; (void)out_size;

    hipMemsetAsync(d_ws, 0, zero_bytes, stream);

    k_count <<<(N_EDGES+255)/256, 256, 0, stream>>>(ei, cnt);
    k_dinv  <<<(N_NODES+255)/256, 256, 0, stream>>>(cnt, dinv);
    k_scanA <<<NSB, 1024, 0, stream>>>(cnt, incl, part);
    k_scanB <<<1, 64, 0, stream>>>(part);
    k_scanC <<<NSB, 1024, 0, stream>>>(cnt, incl, part, offs, cursor);
    k_fill  <<<(N_EDGES+255)/256, 256, 0, stream>>>(ei, dinv, cursor, csr_src, csr_w);

    k_gemm1 <<<(ROWS+63)/64, 256, 0, stream>>>(x, W1, xw);
    k_prop1 <<<1024, 256, 0, stream>>>(xw, offs, csr_src, csr_w, dinv, b1, h, stat1);
    k_bnfin <<<1, 64, 0, stream>>>(stat1, g1, be1, sc1, 64);
    k_bn1_gemm2 <<<(ROWS+31)/32, 256, 0, stream>>>(h, sc1, W2, t2);
    k_prop2 <<<1024, 256, 0, stream>>>(t2, offs, csr_src, csr_w, dinv, b2, x1_out, stat2);
    k_bnfin <<<1, 64, 0, stream>>>(stat2, g2, be2, sc2, 8);
    k_bn2_gemm3 <<<(ROWS+255)/256, 256, 0, stream>>>(x1_out, sc2, W3, t3);
    k_prop3 <<<1024, 256, 0, stream>>>(t3, offs, csr_src, csr_w, dinv, b3, outp);
}

// Round 3
// 514.452 us; speedup vs baseline: 1.1497x; 1.1497x over previous
//
#include <hip/hip_runtime.h>
#include <stdint.h>

#define N_NODES 50000
#define N_EDGES 800000
#define BB 2
#define F0 216
#define ROWS (BB*N_NODES)   // 100000
#define BN_EPS 1e-5f
#define NSB 49              // ceil(N_NODES/1024)

// ---------------- CSR build ----------------
// edge_index arrives as int32 [2, E] (harness stages integer inputs as int32)

__global__ void k_count(const int* __restrict__ ei, int* __restrict__ cnt) {
    int e = blockIdx.x*blockDim.x + threadIdx.x;
    if (e < N_EDGES) {
        int c = ei[N_EDGES + e];
        atomicAdd(&cnt[c], 1);
    }
}

__global__ void k_dinv(const int* __restrict__ cnt, float* __restrict__ dinv) {
    int i = blockIdx.x*blockDim.x + threadIdx.x;
    if (i < N_NODES) dinv[i] = rsqrtf((float)(cnt[i] + 1));  // +1 self loop
}

__global__ void k_scanA(const int* __restrict__ cnt, int* __restrict__ incl, int* __restrict__ part) {
    __shared__ int s[1024];
    int t = threadIdx.x;
    int i = blockIdx.x*1024 + t;
    s[t] = (i < N_NODES) ? cnt[i] : 0;
    __syncthreads();
    for (int off=1; off<1024; off<<=1) {
        int a = (t >= off) ? s[t-off] : 0;
        __syncthreads();
        s[t] += a;
        __syncthreads();
    }
    if (i < N_NODES) incl[i] = s[t];
    if (t == 1023) part[blockIdx.x] = s[t];
}

__global__ void k_scanB(int* part) {
    if (threadIdx.x == 0 && blockIdx.x == 0) {
        int run = 0;
        for (int b=0; b<NSB; b++) { int v = part[b]; part[b] = run; run += v; }
    }
}

__global__ void k_scanC(const int* __restrict__ cnt, const int* __restrict__ incl, const int* __restrict__ part,
                        int* __restrict__ offs, int* __restrict__ cursor) {
    int i = blockIdx.x*1024 + threadIdx.x;
    if (i < N_NODES) {
        int inc = part[blockIdx.x] + incl[i];
        int ex = inc - cnt[i];
        offs[i] = ex; cursor[i] = ex;
        if (i == N_NODES-1) offs[N_NODES] = inc;
    }
}

__global__ void k_fill(const int* __restrict__ ei, const float* __restrict__ dinv,
                       int* __restrict__ cursor, int* __restrict__ csr_src, float* __restrict__ csr_w) {
    int e = blockIdx.x*blockDim.x + threadIdx.x;
    if (e < N_EDGES) {
        int r = ei[e];
        int c = ei[N_EDGES + e];
        int slot = atomicAdd(&cursor[c], 1);
        csr_src[slot] = r;
        csr_w[slot]  = dinv[r];
    }
}

// ---------------- Layer 1 GEMM: xw[100k,64] = x[100k,216] @ W1 ----------------
// v2: x tile TRANSPOSED in LDS (broadcast b128 reads); W hoisted to registers
// in K-chunks of 24 (no global loads in FMA loop, no LDS traffic for W).
#define KC 24
__global__ __launch_bounds__(256,2) void k_gemm1(const float* __restrict__ x, const float* __restrict__ W1,
                                                 float* __restrict__ xw) {
    __shared__ float xs[F0*64];        // xs[k][r], 55296 B -> 2 blocks/CU
    int t = threadIdx.x;
    int row0 = blockIdx.x * 64;

    // stage + transpose: 64 rows x 16 k's per iteration
    int r  = t & 63;
    int kg = t >> 6;                   // 0..3
    bool rowok = (row0 + r) < ROWS;
    const float* xr = x + (size_t)(row0 + r) * F0;
    for (int kb = 0; kb < F0; kb += 16) {
        int k0 = kb + kg*4;
        if (k0 < F0) {
            float4 v; v.x=v.y=v.z=v.w=0.f;
            if (rowok) v = *reinterpret_cast<const float4*>(xr + k0);
            xs[(k0+0)*64 + r] = v.x;
            xs[(k0+1)*64 + r] = v.y;
            xs[(k0+2)*64 + r] = v.z;
            xs[(k0+3)*64 + r] = v.w;
        }
    }
    __syncthreads();

    int o2 = t & 31;                   // cols o2 and o2+32
    int rg = t >> 5;                   // row group 0..7 (8 rows each)
    float acc0[8], acc1[8];
    #pragma unroll
    for (int j=0;j<8;j++){ acc0[j]=0.f; acc1[j]=0.f; }

    for (int kc = 0; kc < F0; kc += KC) {
        float wa[KC], wb[KC];
        #pragma unroll
        for (int kk=0; kk<KC; kk++) {
            wa[kk] = W1[(kc+kk)*64 + o2];
            wb[kk] = W1[(kc+kk)*64 + o2 + 32];
        }
        #pragma unroll
        for (int kk=0; kk<KC; kk++) {
            const float* xk = xs + (kc+kk)*64 + rg*8;
            float4 x0 = *reinterpret_cast<const float4*>(xk);
            float4 x1 = *reinterpret_cast<const float4*>(xk + 4);
            float w0 = wa[kk], w1 = wb[kk];
            acc0[0] += x0.x*w0; acc0[1] += x0.y*w0; acc0[2] += x0.z*w0; acc0[3] += x0.w*w0;
            acc0[4] += x1.x*w0; acc0[5] += x1.y*w0; acc0[6] += x1.z*w0; acc0[7] += x1.w*w0;
            acc1[0] += x0.x*w1; acc1[1] += x0.y*w1; acc1[2] += x0.z*w1; acc1[3] += x0.w*w1;
            acc1[4] += x1.x*w1; acc1[5] += x1.y*w1; acc1[6] += x1.z*w1; acc1[7] += x1.w*w1;
        }
    }

    #pragma unroll
    for (int j=0;j<8;j++) {
        int grow = row0 + rg*8 + j;
        if (grow < ROWS) {
            xw[(size_t)grow*64 + o2]      = acc0[j];
            xw[(size_t)grow*64 + o2 + 32] = acc1[j];
        }
    }
}

// ---------------- Propagate 1 (64 feat) + bias + relu + BN1 stats ----------------
// v2: edge loop unrolled x4 (8 outstanding gathers), grid 2048
__global__ __launch_bounds__(256) void k_prop1(const float* __restrict__ xw, const int* __restrict__ offs,
                       const int* __restrict__ csr_src, const float* __restrict__ csr_w,
                       const float* __restrict__ dinv, const float* __restrict__ b1,
                       float* __restrict__ h, float* __restrict__ stat) {
    __shared__ float lsum[64], lsq[64];
    int t = threadIdx.x;
    if (t < 64) { lsum[t]=0.f; lsq[t]=0.f; }
    __syncthreads();
    int f = t & 63;
    int wid = blockIdx.x*4 + (t>>6);
    int nwaves = gridDim.x*4;
    float bias = b1[f];
    float ls=0.f, lq=0.f;
    for (int d = wid; d < N_NODES; d += nwaves) {
        int s0 = offs[d], s1 = offs[d+1];
        float a0=0.f, a1=0.f, p0=0.f, p1=0.f, q0=0.f, q1=0.f, r0=0.f, r1=0.f;
        int e = s0;
        for (; e+4 <= s1; e += 4) {
            int i0=csr_src[e], i1=csr_src[e+1], i2=csr_src[e+2], i3=csr_src[e+3];
            float w0=csr_w[e], w1=csr_w[e+1], w2=csr_w[e+2], w3=csr_w[e+3];
            a0 += w0*xw[(size_t)i0*64+f];  a1 += w0*xw[(size_t)(N_NODES+i0)*64+f];
            p0 += w1*xw[(size_t)i1*64+f];  p1 += w1*xw[(size_t)(N_NODES+i1)*64+f];
            q0 += w2*xw[(size_t)i2*64+f];  q1 += w2*xw[(size_t)(N_NODES+i2)*64+f];
            r0 += w3*xw[(size_t)i3*64+f];  r1 += w3*xw[(size_t)(N_NODES+i3)*64+f];
        }
        for (; e < s1; e++) {
            int src = csr_src[e]; float w = csr_w[e];
            a0 += w*xw[(size_t)src*64+f];  a1 += w*xw[(size_t)(N_NODES+src)*64+f];
        }
        a0 += p0 + q0 + r0;
        a1 += p1 + q1 + r1;
        float sd = dinv[d];
        a0 += sd * xw[(size_t)d*64 + f];
        a1 += sd * xw[(size_t)(N_NODES+d)*64 + f];
        float h0 = fmaxf(sd*a0 + bias, 0.f);
        float h1 = fmaxf(sd*a1 + bias, 0.f);
        h[(size_t)d*64 + f] = h0;
        h[(size_t)(N_NODES+d)*64 + f] = h1;
        ls += h0 + h1;
        lq += h0*h0 + h1*h1;
    }
    atomicAdd(&lsum[f], ls);
    atomicAdd(&lsq[f], lq);
    __syncthreads();
    if (t < 64) {
        atomicAdd(&stat[t],     lsum[t]);
        atomicAdd(&stat[64+t],  lsq[t]);
    }
}

// ---------------- BN finalize -> scale/shift ----------------
__global__ void k_bnfin(const float* __restrict__ stat, const float* __restrict__ g,
                        const float* __restrict__ be, float* __restrict__ sc, int C) {
    int f = threadIdx.x;
    if (f < C) {
        float inv_n = 1.0f / (float)(BB*N_NODES);
        float mean = stat[f]*inv_n;
        float var  = stat[C+f]*inv_n - mean*mean;
        float is   = rsqrtf(var + BN_EPS);
        float scale = g[f]*is;
        sc[f]   = scale;
        sc[C+f] = be[f] - mean*scale;
    }
}

// ---------------- BN1 apply + GEMM2 (64->8) ----------------
__global__ __launch_bounds__(256) void k_bn1_gemm2(const float* __restrict__ h, const float* __restrict__ sc1,
                        const float* __restrict__ W2, float* __restrict__ t2) {
    __shared__ float hs[32][68];
    __shared__ float w2s[64*8];
    int t = threadIdx.x;
    for (int i=t; i<512; i+=256) w2s[i] = W2[i];
    int row0 = blockIdx.x*32;
    for (int idx=t; idx<2048; idx+=256) {
        int r = idx>>6, f = idx&63;
        int grow = row0 + r;
        hs[r][f] = (grow < ROWS) ? h[(size_t)grow*64+f]*sc1[f] + sc1[64+f] : 0.f;
    }
    __syncthreads();
    int r = t >> 3, o = t & 7;
    float acc = 0.f;
    #pragma unroll
    for (int f=0; f<64; f++) acc += hs[r][f] * w2s[f*8+o];
    int grow = row0 + r;
    if (grow < ROWS) t2[(size_t)grow*8 + o] = acc;
}

// ---------------- Propagate 2 (8 feat) -> x1 out; relu + BN2 stats ----------------
__global__ __launch_bounds__(256) void k_prop2(const float* __restrict__ t2, const int* __restrict__ offs,
                       const int* __restrict__ csr_src, const float* __restrict__ csr_w,
                       const float* __restrict__ dinv, const float* __restrict__ b2,
                       float* __restrict__ x1_out, float* __restrict__ stat) {
    __shared__ float lsum[8], lsq[8];
    int t = threadIdx.x;
    if (t < 8) { lsum[t]=0.f; lsq[t]=0.f; }
    __syncthreads();
    int lane = t & 63;
    int o = lane & 7, b = (lane>>3)&1, es = lane>>4;   // 4 edge-lanes
    int wid = blockIdx.x*4 + (t>>6);
    int nwaves = gridDim.x*4;
    float bias = b2[o];
    float ls=0.f, lq=0.f;
    for (int d=wid; d<N_NODES; d+=nwaves) {
        int s0=offs[d], s1=offs[d+1];
        float accA=0.f, accB=0.f;
        int e = s0 + es;
        for (; e+4 < s1; e += 8) {
            accA += csr_w[e]   * t2[(size_t)(b*N_NODES+csr_src[e])*8 + o];
            accB += csr_w[e+4] * t2[(size_t)(b*N_NODES+csr_src[e+4])*8 + o];
        }
        if (e < s1) accA += csr_w[e] * t2[(size_t)(b*N_NODES+csr_src[e])*8 + o];
        float acc = accA + accB;
        acc += __shfl_xor(acc, 16, 64);
        acc += __shfl_xor(acc, 32, 64);
        float sd = dinv[d];
        float val = sd*(acc + sd*t2[(size_t)(b*N_NODES+d)*8 + o]) + bias;
        if (es == 0) {
            x1_out[(size_t)(b*N_NODES+d)*8 + o] = val;
            float rv = fmaxf(val, 0.f);
            ls += rv; lq += rv*rv;
        }
    }
    if (es == 0) { atomicAdd(&lsum[o], ls); atomicAdd(&lsq[o], lq); }
    __syncthreads();
    if (t < 8) { atomicAdd(&stat[t], lsum[t]); atomicAdd(&stat[8+t], lsq[t]); }
}

// ---------------- BN2 apply + GEMM3 (8->3), padded to 4 ----------------
__global__ void k_bn2_gemm3(const float* __restrict__ x1, const float* __restrict__ sc2,
                            const float* __restrict__ W3, float* __restrict__ t3) {
    int rowi = blockIdx.x*blockDim.x + threadIdx.x;
    if (rowi < ROWS) {
        float v[8];
        #pragma unroll
        for (int o=0;o<8;o++) {
            float r = fmaxf(x1[(size_t)rowi*8+o], 0.f);
            v[o] = r*sc2[o] + sc2[8+o];
        }
        #pragma unroll
        for (int c=0;c<3;c++) {
            float acc=0.f;
            #pragma unroll
            for (int o=0;o<8;o++) acc += v[o]*W3[o*3+c];
            t3[(size_t)rowi*4+c] = acc;
        }
        t3[(size_t)rowi*4+3] = 0.f;
    }
}

// ---------------- Propagate 3 (3 feat) + b3 -> final out ----------------
__global__ __launch_bounds__(256) void k_prop3(const float* __restrict__ t3, const int* __restrict__ offs,
                       const int* __restrict__ csr_src, const float* __restrict__ csr_w,
                       const float* __restrict__ dinv, const float* __restrict__ b3,
                       float* __restrict__ outp) {
    int t = threadIdx.x;
    int lane = t & 63;
    int c = lane & 3, b = (lane>>2)&1, es = lane>>3;   // 8 edge-lanes
    int wid = blockIdx.x*4 + (t>>6);
    int nwaves = gridDim.x*4;
    float bias = (c<3) ? b3[c] : 0.f;
    for (int d=wid; d<N_NODES; d+=nwaves) {
        int s0=offs[d], s1=offs[d+1];
        float accA=0.f, accB=0.f;
        int e = s0 + es;
        for (; e+8 < s1; e += 16) {
            accA += csr_w[e]   * t3[(size_t)(b*N_NODES+csr_src[e])*4 + c];
            accB += csr_w[e+8] * t3[(size_t)(b*N_NODES+csr_src[e+8])*4 + c];
        }
        if (e < s1) accA += csr_w[e] * t3[(size_t)(b*N_NODES+csr_src[e])*4 + c];
        float acc = accA + accB;
        acc += __shfl_xor(acc, 8, 64);
        acc += __shfl_xor(acc, 16, 64);
        acc += __shfl_xor(acc, 32, 64);
        float sd = dinv[d];
        float val = sd*(acc + sd*t3[(size_t)(b*N_NODES+d)*4 + c]) + bias;
        if (es == 0 && c < 3) outp[(size_t)(b*N_NODES+d)*3 + c] = val;
    }
}

// ---------------- launch ----------------
static inline size_t align256(size_t x){ return (x + 255) & ~(size_t)255; }

extern "C" void kernel_launch(void* const* d_in, const int* in_sizes, int n_in,
                              void* d_out, int out_size, void* d_ws, size_t ws_size,
                              hipStream_t stream) {
    const float* x   = (const float*)d_in[0];
    const float* W1  = (const float*)d_in[1];
    const float* b1  = (const float*)d_in[2];
    const float* g1  = (const float*)d_in[3];
    const float* be1 = (const float*)d_in[4];
    const float* W2  = (const float*)d_in[5];
    const float* b2  = (const float*)d_in[6];
    const float* g2  = (const float*)d_in[7];
    const float* be2 = (const float*)d_in[8];
    const float* W3  = (const float*)d_in[9];
    const float* b3  = (const float*)d_in[10];
    const int*   ei  = (const int*)d_in[11];     // int32 [2, E]

    float* outp   = (float*)d_out;                 // [B,N,3]
    float* x1_out = (float*)d_out + BB*N_NODES*3;  // [B,N,8]

    char* w = (char*)d_ws;
    size_t off = 0;
    auto alloc = [&](size_t bytes) { void* p = w + off; off = align256(off + bytes); return p; };
    int*   cnt    = (int*)  alloc(N_NODES*4);
    float* stat1  = (float*)alloc(128*4);
    float* stat2  = (float*)alloc(16*4);
    size_t zero_bytes = off;
    float* dinv   = (float*)alloc(N_NODES*4);
    int*   incl   = (int*)  alloc(N_NODES*4);
    int*   part   = (int*)  alloc(64*4);
    int*   offs   = (int*)  alloc((N_NODES+1)*4);
    int*   cursor = (int*)  alloc(N_NODES*4);
    int*   csr_src= (int*)  alloc((size_t)N_EDGES*4);
    float* csr_w  = (float*)alloc((size_t)N_EDGES*4);
    float* xw     = (float*)alloc((size_t)ROWS*64*4);
    float* h      = (float*)alloc((size_t)ROWS*64*4);
    float* sc1    = (float*)alloc(128*4);
    float* sc2    = (float*)alloc(16*4);
    float* t2     = xw;      // alias: xw dead after k_prop1
    float* t3     = h;       // alias: h dead after k_bn1_gemm2
    (void)ws_size; (void)in_sizes; (void)n_in; (void)out_size;

    hipMemsetAsync(d_ws, 0, zero_bytes, stream);

    k_count <<<(N_EDGES+255)/256, 256, 0, stream>>>(ei, cnt);
    k_dinv  <<<(N_NODES+255)/256, 256, 0, stream>>>(cnt, dinv);
    k_scanA <<<NSB, 1024, 0, stream>>>(cnt, incl, part);
    k_scanB <<<1, 64, 0, stream>>>(part);
    k_scanC <<<NSB, 1024, 0, stream>>>(cnt, incl, part, offs, cursor);
    k_fill  <<<(N_EDGES+255)/256, 256, 0, stream>>>(ei, dinv, cursor, csr_src, csr_w);

    k_gemm1 <<<(ROWS+63)/64, 256, 0, stream>>>(x, W1, xw);
    k_prop1 <<<2048, 256, 0, stream>>>(xw, offs, csr_src, csr_w, dinv, b1, h, stat1);
    k_bnfin <<<1, 64, 0, stream>>>(stat1, g1, be1, sc1, 64);
    k_bn1_gemm2 <<<(ROWS+31)/32, 256, 0, stream>>>(h, sc1, W2, t2);
    k_prop2 <<<2048, 256, 0, stream>>>(t2, offs, csr_src, csr_w, dinv, b2, x1_out, stat2);
    k_bnfin <<<1, 64, 0, stream>>>(stat2, g2, be2, sc2, 8);
    k_bn2_gemm3 <<<(ROWS+255)/256, 256, 0, stream>>>(x1_out, sc2, W3, t3);
    k_prop3 <<<2048, 256, 0, stream>>>(t3, offs, csr_src, csr_w, dinv, b3, outp);
}